// Round 8
// baseline (617.882 us; speedup 1.0000x reference)
//
#include <hip/hip_runtime.h>
#include <hip/hip_bf16.h>
#include <math.h>

#define KNN 20
#define CHSZ 2048   // candidate chunk size for distance matrix

typedef __attribute__((ext_vector_type(8))) short bf16x8_t;
typedef __attribute__((ext_vector_type(4))) float f32x4_t;

// bf16 split helpers (RNE)
__device__ __forceinline__ unsigned short f2bf(float f) {
    unsigned u = __float_as_uint(f);
    u += 0x7fffu + ((u >> 16) & 1u);
    return (unsigned short)(u >> 16);
}
__device__ __forceinline__ float bf2f(unsigned short h) {
    return __uint_as_float((unsigned)h << 16);
}

// async global->LDS, 16 B per lane; dest = wave-uniform base + lane*16
__device__ __forceinline__ void gload_lds16(const void* g, void* l) {
    auto gp = reinterpret_cast<const __attribute__((address_space(1))) unsigned*>(
        reinterpret_cast<uintptr_t>(g));
    auto lp = reinterpret_cast<__attribute__((address_space(3))) unsigned*>(
        reinterpret_cast<uintptr_t>(l));
    __builtin_amdgcn_global_load_lds(gp, lp, 16, 0, 0);
}

// 64-lane bitonic ascending sort of one float per lane; returns lane-19 value.
// tau = 20th order statistic of the 64 per-lane minima over the scanned set.
// Validity: the set's top-20 occupy <=20 lanes; each such lane's min <= its
// smallest top-20 member, all other lane minima > d20(set) -> the 20th
// smallest lane-min >= d20(set) >= global d20. Filtering with v <= tau never
// rejects a final top-20 member.
__device__ __forceinline__ float seed_tau(float mv, int l) {
#pragma unroll
    for (int k = 2; k <= 64; k <<= 1) {
#pragma unroll
        for (int j = k >> 1; j > 0; j >>= 1) {
            float o = __shfl_xor(mv, j);
            bool keepMin = (((l & j) == 0) == ((l & k) == 0));
            mv = keepMin ? fminf(mv, o) : fmaxf(mv, o);
        }
    }
    return __shfl(mv, 19);
}

// ---------------------------------------------------------------- rowsq
template<int C>
__global__ void rowsq_kernel(const float* __restrict__ x, float* __restrict__ sq, int N) {
    int i = blockIdx.x * blockDim.x + threadIdx.x;
    if (i >= N) return;
    float s = 0.f;
    if constexpr (C == 64) {
        const float4* p = reinterpret_cast<const float4*>(x + (size_t)i * C);
#pragma unroll
        for (int c = 0; c < 16; ++c) {
            float4 v = p[c];
            s += v.x * v.x + v.y * v.y + v.z * v.z + v.w * v.w;
        }
    } else {
#pragma unroll
        for (int c = 0; c < C; ++c) { float v = x[(size_t)i * C + c]; s += v * v; }
    }
    sq[i] = s;
}

// ---------------------------------------------------------------- triple-bf16 split
// fp32 = h + l + m (exactly, 3x8 significand bits). Xs[row][0:64)=h,
// [64:128)=l, [128:192)=m.
__global__ void xsplit3_kernel(const float* __restrict__ X,
                               unsigned short* __restrict__ Xs, int N) {
    int t = blockIdx.x * 256 + threadIdx.x;
    if (t >= N * 64) return;
    int r = t >> 6, c = t & 63;
    float v = X[t];
    unsigned short h = f2bf(v);
    float r1 = v - bf2f(h);
    unsigned short lo = f2bf(r1);
    float r2 = r1 - bf2f(lo);
    unsigned short mm = f2bf(r2);
    Xs[(size_t)r * 192 + c] = h;
    Xs[(size_t)r * 192 + 64 + c] = lo;
    Xs[(size_t)r * 192 + 128 + c] = mm;
}

// ---------------------------------------------------------------- dist MFMA (C=64)
// D[m][n] = sq[m] + sq[j] - 2 * dot(X[m], X[j]), dot via 6-term split-bf16
// MFMA (terms {mh, hh, hl, hm, lh, ll}; dropped terms <= 2^-25 rel).
// 256x128 output tile per block: wave w owns rows [w*64, w*64+64) x all 128
// cols (acc[4][8]). B: all 3 segs staged ONCE (48 KB); A: staged per-segment
// (32 KB) -> 80 KB LDS, 2 blocks/CU. Staging bytes/output -25% and MFMA per
// barrier 2x vs the 128x128 tile. Term order and per-element K-accumulation
// order identical to the verified 128-tile version.
__global__ __launch_bounds__(256) void dist_mfma_kernel(
    const unsigned short* __restrict__ Xs, const float* __restrict__ sq,
    float* __restrict__ D, int chunk_base) {
    __shared__ __align__(16) unsigned short As[256 * 64];       // 32 KB (current A-seg)
    __shared__ __align__(16) unsigned short Bs[3 * 128 * 64];   // 48 KB (segs h,l,m)
    const int tid = threadIdx.x;
    const int w = tid >> 6, l = tid & 63;
    const int m0 = blockIdx.y * 256;
    const int n0 = blockIdx.x * 128;          // chunk-local
    const int jb = chunk_base + n0;           // global candidate base
    const int lr = l >> 3;
    const int swz = ((l & 7) ^ lr) * 8;
    const int frow = l & 15;
    const int fq = l >> 4;
    const int fswz = l & 7;

    f32x4_t acc[4][8];
#pragma unroll
    for (int a = 0; a < 4; ++a)
#pragma unroll
        for (int b = 0; b < 8; ++b) acc[a][b] = (f32x4_t){0.f, 0.f, 0.f, 0.f};

    // stage B: all three segs (sub-buffer 0=h(+0), 1=l(+64), 2=m(+128))
#pragma unroll
    for (int sgi = 0; sgi < 3; ++sgi) {
#pragma unroll
        for (int s = 0; s < 4; ++s) {
            int row = w * 32 + s * 8;
            gload_lds16(Xs + (size_t)(jb + row + lr) * 192 + sgi * 64 + swz,
                        (void*)(Bs + sgi * 8192 + row * 64));
        }
    }

    // A-seg order m(+128), h(+0), l(+64); B partners {h} / {h,l,m} / {h,l}
#pragma unroll
    for (int ai = 0; ai < 3; ++ai) {
        constexpr int aoffs[3] = {128, 0, 64};
        constexpr int bcnts[3] = {1, 3, 2};
        if (ai) __syncthreads();          // all waves done reading prior As
#pragma unroll
        for (int s = 0; s < 8; ++s) {
            int row = w * 64 + s * 8;
            gload_lds16(Xs + (size_t)(m0 + row + lr) * 192 + aoffs[ai] + swz,
                        (void*)(As + row * 64));
        }
        __syncthreads();                   // staging visible (incl. B on ai=0)
        bf16x8_t af[2][4];
#pragma unroll
        for (int ks = 0; ks < 2; ++ks) {
            const int o = (ks * 4 + fq) ^ fswz;
#pragma unroll
            for (int tm = 0; tm < 4; ++tm)
                af[ks][tm] = *reinterpret_cast<const bf16x8_t*>(
                    As + (w * 64 + tm * 16 + frow) * 64 + o * 8);
        }
#pragma unroll
        for (int bi = 0; bi < bcnts[ai]; ++bi) {
            const unsigned short* Bseg = Bs + bi * 8192;
#pragma unroll
            for (int ks = 0; ks < 2; ++ks) {
                const int o = (ks * 4 + fq) ^ fswz;
                bf16x8_t bf[8];
#pragma unroll
                for (int tn = 0; tn < 8; ++tn)
                    bf[tn] = *reinterpret_cast<const bf16x8_t*>(
                        Bseg + (tn * 16 + frow) * 64 + o * 8);
#pragma unroll
                for (int tm = 0; tm < 4; ++tm)
#pragma unroll
                    for (int tn = 0; tn < 8; ++tn)
                        acc[tm][tn] = __builtin_amdgcn_mfma_f32_16x16x32_bf16(
                            af[ks][tm], bf[tn], acc[tm][tn], 0, 0, 0);
            }
        }
    }

    // epilogue: C/D layout col=lane&15, row=(lane>>4)*4+reg
    float sn[8]; int jn[8], nc[8];
#pragma unroll
    for (int tn = 0; tn < 8; ++tn) {
        nc[tn] = tn * 16 + (l & 15);
        jn[tn] = jb + nc[tn];
        sn[tn] = sq[jn[tn]];
    }
#pragma unroll
    for (int tm = 0; tm < 4; ++tm) {
#pragma unroll
        for (int r = 0; r < 4; ++r) {
            int m = m0 + w * 64 + tm * 16 + (l >> 4) * 4 + r;
            float sm = sq[m];
#pragma unroll
            for (int tn = 0; tn < 8; ++tn) {
                float val = sm + sn[tn] - 2.f * acc[tm][tn][r];
                if (m == jn[tn]) val = INFINITY;
                D[(size_t)m * CHSZ + n0 + nc[tn]] = val;
            }
        }
    }
}

// ---------------------------------------------------------------- knn select (C=64 path)
// One wave per point; distributed sorted top-20 (lanes 0..19), lex (d,idx)
// order == jax.lax.top_k tie-break. All 32 values register-resident; per-chunk
// tau (20th of lane minima, exact bound); tf = min(tau_chunk, carried d19).
__global__ __launch_bounds__(256) void knn_select_kernel(
    const float* __restrict__ D, float* __restrict__ sd, int* __restrict__ si,
    int* __restrict__ nbrs, int chunk_base, int first, int last) {
    const int tid = threadIdx.x;
    const int w = tid >> 6, l = tid & 63;
    const int p = blockIdx.x * 4 + w;

    float dl = INFINITY; int il = 0x7fffffff;
    if (!first && l < KNN) { dl = sd[(size_t)p * KNN + l]; il = si[(size_t)p * KNN + l]; }
    float d19 = __shfl(dl, 19);

    const float4* Drow = reinterpret_cast<const float4*>(D + (size_t)p * CHSZ);
    float4 v[8];
#pragma unroll
    for (int b = 0; b < 8; ++b) v[b] = Drow[b * 64 + l];

    // per-chunk tau from the register-resident values (diag already INF)
    float mn = INFINITY;
#pragma unroll
    for (int b = 0; b < 8; ++b)
        mn = fminf(mn, fminf(fminf(v[b].x, v[b].y), fminf(v[b].z, v[b].w)));
    const float tau = seed_tau(mn, l);
    const float tf = fminf(tau, d19);

#pragma unroll
    for (int b = 0; b < 8; ++b) {
        bool q0 = v[b].x <= tf, q1 = v[b].y <= tf, q2 = v[b].z <= tf, q3 = v[b].w <= tf;
        unsigned long long anyb = __ballot(q0 | q1 | q2 | q3);
        if (!anyb) continue;
#pragma unroll
        for (int qq = 0; qq < 4; ++qq) {
            float vq = (qq == 0) ? v[b].x : (qq == 1) ? v[b].y : (qq == 2) ? v[b].z : v[b].w;
            unsigned long long bal = __ballot((qq == 0) ? q0 : (qq == 1) ? q1 : (qq == 2) ? q2 : q3);
            while (bal) {
                int ln = __ffsll((unsigned long long)bal) - 1;
                bal &= bal - 1;
                float cv = __shfl(vq, ln);
                int cj = chunk_base + b * 256 + 4 * ln + qq;
                bool cmp = (dl < cv) || (dl == cv && il < cj);
                unsigned long long cb = __ballot(cmp) & 0xFFFFFull;
                int r = __popcll(cb);
                float sdl = __shfl_up(dl, 1);
                int sil = __shfl_up(il, 1);
                if (l == r) { dl = cv; il = cj; }
                else if (l > r && l < KNN) { dl = sdl; il = sil; }
            }
        }
    }
    if (l < KNN) {
        sd[(size_t)p * KNN + l] = dl;
        si[(size_t)p * KNN + l] = il;
        if (last) nbrs[(size_t)p * KNN + l] = il;
    }
}

// ---------------------------------------------------------------- knn fused (C=3), 2 points/wave
// Multi-query two-pass (proven round-3/4 structure), but 2 points per wave
// instead of 4: grid N/8 = 1024 blocks -> 4 waves/SIMD (vs 2), converting
// the ~46% latency-stall into issue while keeping total bitonic count and
// structure identical (no merge phase, no LDS).
__global__ __launch_bounds__(256) void knn3_fused_kernel(
    const float* __restrict__ X, const float* __restrict__ sq,
    int* __restrict__ nbrs, int N) {
    const int tid = threadIdx.x;
    const int w = tid >> 6, l = tid & 63;
    const int p0 = blockIdx.x * 8 + w * 2;   // points p0, p0+1
    float qx[2], qy[2], qz[2], sp4[2];
#pragma unroll
    for (int pp = 0; pp < 2; ++pp) {
        qx[pp] = X[(size_t)(p0 + pp) * 3];
        qy[pp] = X[(size_t)(p0 + pp) * 3 + 1];
        qz[pp] = X[(size_t)(p0 + pp) * 3 + 2];
        sp4[pp] = sq[p0 + pp];
    }
    const int ptile = p0 & ~255;   // both points share this 256-tile

    // ---- pass 1: per-lane minima for both points
    float mn[2];
#pragma unroll
    for (int pp = 0; pp < 2; ++pp) mn[pp] = INFINITY;
    {
        const float4* xr0 = reinterpret_cast<const float4*>(X + (size_t)(4 * l) * 3);
        float4 nr0 = xr0[0], nr1 = xr0[1], nr2 = xr0[2];
        float4 nsj = *reinterpret_cast<const float4*>(sq + 4 * l);
#pragma unroll 1
        for (int j0 = 0; j0 < N; j0 += 256) {
            const int jl = j0 + 4 * l;
            float4 r0 = nr0, r1 = nr1, r2 = nr2, sj = nsj;
            if (j0 + 256 < N) {
                const float4* xn = reinterpret_cast<const float4*>(X + (size_t)(jl + 256) * 3);
                nr0 = xn[0]; nr1 = xn[1]; nr2 = xn[2];
                nsj = *reinterpret_cast<const float4*>(sq + jl + 256);
            }
            float cx[4] = {r0.x, r0.w, r1.z, r2.y};
            float cy[4] = {r0.y, r1.x, r1.w, r2.z};
            float cz[4] = {r0.z, r1.y, r2.x, r2.w};
            float sjc[4] = {sj.x, sj.y, sj.z, sj.w};
            float v[2][4];
#pragma unroll
            for (int pp = 0; pp < 2; ++pp)
#pragma unroll
                for (int c = 0; c < 4; ++c) {
                    float t = qx[pp] * cx[c];
                    t = fmaf(qy[pp], cy[c], t);
                    t = fmaf(qz[pp], cz[c], t);
                    v[pp][c] = fmaf(-2.f, t, sp4[pp] + sjc[c]);
                }
            if (j0 == ptile) {
#pragma unroll
                for (int pp = 0; pp < 2; ++pp)
#pragma unroll
                    for (int c = 0; c < 4; ++c)
                        if (jl + c == p0 + pp) v[pp][c] = INFINITY;
            }
#pragma unroll
            for (int pp = 0; pp < 2; ++pp)
                mn[pp] = fminf(mn[pp], fminf(fminf(v[pp][0], v[pp][1]),
                                             fminf(v[pp][2], v[pp][3])));
        }
    }
    float tau[2];
#pragma unroll
    for (int pp = 0; pp < 2; ++pp) tau[pp] = seed_tau(mn[pp], l);

    // ---- pass 2: filter with constant tau[pp] + exact lex insert
    float dl[2]; int il[2];
#pragma unroll
    for (int pp = 0; pp < 2; ++pp) { dl[pp] = INFINITY; il[pp] = 0x7fffffff; }
    const float4* xr0 = reinterpret_cast<const float4*>(X + (size_t)(4 * l) * 3);
    float4 nr0 = xr0[0], nr1 = xr0[1], nr2 = xr0[2];
    float4 nsj = *reinterpret_cast<const float4*>(sq + 4 * l);

#pragma unroll 1
    for (int j0 = 0; j0 < N; j0 += 256) {
        const int jl = j0 + 4 * l;
        float4 r0 = nr0, r1 = nr1, r2 = nr2, sj = nsj;
        if (j0 + 256 < N) {
            const float4* xn = reinterpret_cast<const float4*>(X + (size_t)(jl + 256) * 3);
            nr0 = xn[0]; nr1 = xn[1]; nr2 = xn[2];
            nsj = *reinterpret_cast<const float4*>(sq + jl + 256);
        }
        float cx[4] = {r0.x, r0.w, r1.z, r2.y};
        float cy[4] = {r0.y, r1.x, r1.w, r2.z};
        float cz[4] = {r0.z, r1.y, r2.x, r2.w};
        float sjc[4] = {sj.x, sj.y, sj.z, sj.w};
        float v[2][4];
#pragma unroll
        for (int pp = 0; pp < 2; ++pp)
#pragma unroll
            for (int c = 0; c < 4; ++c) {
                float t = qx[pp] * cx[c];
                t = fmaf(qy[pp], cy[c], t);
                t = fmaf(qz[pp], cz[c], t);
                v[pp][c] = fmaf(-2.f, t, sp4[pp] + sjc[c]);
            }
        if (j0 == ptile) {
#pragma unroll
            for (int pp = 0; pp < 2; ++pp)
#pragma unroll
                for (int c = 0; c < 4; ++c)
                    if (jl + c == p0 + pp) v[pp][c] = INFINITY;
        }
#pragma unroll
        for (int pp = 0; pp < 2; ++pp) {
            bool q0 = v[pp][0] <= tau[pp], q1 = v[pp][1] <= tau[pp];
            bool q2 = v[pp][2] <= tau[pp], q3 = v[pp][3] <= tau[pp];
            unsigned long long anyb = __ballot(q0 | q1 | q2 | q3);
            if (!anyb) continue;
#pragma unroll
            for (int qq = 0; qq < 4; ++qq) {
                float vq = v[pp][qq];
                unsigned long long bal = __ballot((qq == 0) ? q0 : (qq == 1) ? q1 : (qq == 2) ? q2 : q3);
                while (bal) {
                    int ln = __ffsll((unsigned long long)bal) - 1;
                    bal &= bal - 1;
                    float cv = __shfl(vq, ln);
                    int cj = j0 + 4 * ln + qq;
                    bool cmp = (dl[pp] < cv) || (dl[pp] == cv && il[pp] < cj);
                    unsigned long long cb = __ballot(cmp) & 0xFFFFFull;
                    int r = __popcll(cb);
                    float sdl = __shfl_up(dl[pp], 1);
                    int sil = __shfl_up(il[pp], 1);
                    if (l == r) { dl[pp] = cv; il[pp] = cj; }
                    else if (l > r && l < KNN) { dl[pp] = sdl; il[pp] = sil; }
                }
            }
        }
    }
    if (l < KNN) {
#pragma unroll
        for (int pp = 0; pp < 2; ++pp)
            nbrs[(size_t)(p0 + pp) * KNN + l] = il[pp];
    }
}

// ---------------------------------------------------------------- edgeconv (factored, fp32 exact)
template<int C>
__global__ void prep_w_kernel(const float* __restrict__ w, const float* __restrict__ b,
                              float* __restrict__ WW, float* __restrict__ bb) {
    int t = blockIdx.x * blockDim.x + threadIdx.x;
    if (t < 128) bb[t] = (t < 64) ? b[t] : 0.f;
    if (t >= C * 128) return;
    int c = t >> 7, f = t & 127;
    WW[t] = (f < 64) ? (w[c * 64 + f] - w[(C + c) * 64 + f]) : w[(C + c) * 64 + (f - 64)];
}

template<int C, int ROWS>
__global__ __launch_bounds__(128) void ec_gemm_kernel(
    const float* __restrict__ x, const float* __restrict__ WW,
    const float* __restrict__ bb, float* __restrict__ AB, int N) {
    __shared__ float Ws[C * 128];
    __shared__ float xs[ROWS * C];
    const int tid = threadIdx.x;
    const int r0 = blockIdx.x * ROWS;
    for (int idx = tid; idx < C * 32; idx += 128)
        reinterpret_cast<float4*>(Ws)[idx] = reinterpret_cast<const float4*>(WW)[idx];
    for (int idx = tid; idx < ROWS * C / 4; idx += 128)
        reinterpret_cast<float4*>(xs)[idx] =
            reinterpret_cast<const float4*>(x + (size_t)r0 * C)[idx];
    __syncthreads();
    const float bias = bb[tid];
#pragma unroll 1
    for (int r = 0; r < ROWS; ++r) {
        float acc = bias;
#pragma unroll
        for (int c = 0; c < C; ++c) acc = fmaf(xs[r * C + c], Ws[c * 128 + tid], acc);
        AB[(size_t)(r0 + r) * 128 + tid] = acc;
    }
}

__global__ __launch_bounds__(256) void ec_max_kernel(
    const float* __restrict__ AB, const int* __restrict__ nbrs,
    float* __restrict__ out, int N) {
    const int tid = threadIdx.x;
    const int w = tid >> 6, f = tid & 63;
    const int i = blockIdx.x * 4 + w;
    const float a = AB[(size_t)i * 128 + f];
    const int* nb = nbrs + (size_t)i * KNN;
    float m = -3.4e38f;
#pragma unroll
    for (int j = 0; j < KNN; ++j) {
        int n = nb[j];
        m = fmaxf(m, AB[(size_t)n * 128 + 64 + f]);
    }
    out[(size_t)i * 64 + f] = fmaxf(a + m, 0.f);
}

// ---------------------------------------------------------------- concat + split to bf16 hi/lo
__global__ void concat_split_kernel(const float* __restrict__ a, const float* __restrict__ b,
                                    const float* __restrict__ c,
                                    unsigned short* __restrict__ hi, unsigned short* __restrict__ lo,
                                    int N) {
    int t = blockIdx.x * blockDim.x + threadIdx.x;
    if (t >= N * 192) return;
    int r = t / 192, cc = t % 192;
    float v;
    if (cc < 64) v = a[(size_t)r * 64 + cc];
    else if (cc < 128) v = b[(size_t)r * 64 + cc - 64];
    else v = c[(size_t)r * 64 + cc - 128];
    unsigned short h = f2bf(v);
    hi[t] = h;
    lo[t] = f2bf(v - bf2f(h));
}

// ---------------------------------------------------------------- weight split: BT[F][3K]
__global__ void prep_bsplit_kernel(const float* __restrict__ W, unsigned short* __restrict__ BT,
                                   int K, int F) {
    int t = blockIdx.x * 256 + threadIdx.x;
    int K3 = 3 * K;
    if (t >= F * K3) return;
    int n = t / K3, kp = t - n * K3;
    int seg = kp / K;
    int k = kp - seg * K;
    float v = W[(size_t)k * F + n];
    unsigned short h = f2bf(v);
    BT[t] = (seg == 1) ? f2bf(v - bf2f(h)) : h;
}

// ---------------------------------------------------------------- split-bf16 MFMA GEMM
// Per-wave tile WM x WN (frag counts FM=WM/16, FN=WN/16), 4 waves per block.
template<int BM, int BN, int WM, int WN, int SPLIT>
__global__ __launch_bounds__(256) void mfma_gemm_kernel(
    const unsigned short* __restrict__ Ahi, const unsigned short* __restrict__ Alo,
    const unsigned short* __restrict__ BT, const float* __restrict__ bias,
    float* __restrict__ Cf, unsigned short* __restrict__ Chi, unsigned short* __restrict__ Clo,
    int M, int N, int K) {
    constexpr int WR = BM / WM, WC = BN / WN;
    static_assert(WR * WC == 4, "4 waves");
    constexpr int FM = WM / 16, FN = WN / 16;
    __shared__ __align__(16) unsigned short As[BM * 64];
    __shared__ __align__(16) unsigned short Bs[BN * 64];
    const int tid = threadIdx.x;
    const int w = tid >> 6, l = tid & 63;
    const int wr = w % WR, wc = w / WR;
    const int m0 = blockIdx.y * BM, n0 = blockIdx.x * BN;
    const int K3 = 3 * K;

    f32x4_t acc[FM][FN];
#pragma unroll
    for (int a = 0; a < FM; ++a)
#pragma unroll
        for (int b = 0; b < FN; ++b) acc[a][b] = (f32x4_t){0.f, 0.f, 0.f, 0.f};

    const int lr = l >> 3;
    const int swz = ((l & 7) ^ lr) * 8;
    const int frow = l & 15;
    const int fq = l >> 4;
    const int fswz = l & 7;

    for (int kt = 0; kt < K3 / 64; ++kt) {
        const int kk = kt * 64;
        const unsigned short* srcA; int k0;
        if (kk < K)            { srcA = Ahi; k0 = kk; }
        else if (kk < 2 * K)   { srcA = Ahi; k0 = kk - K; }
        else                   { srcA = Alo; k0 = kk - 2 * K; }
#pragma unroll
        for (int t = 0; t < BM / 32; ++t) {
            int row = w * (BM / 4) + t * 8;
            gload_lds16(srcA + (size_t)(m0 + row + lr) * K + k0 + swz,
                        (void*)(As + row * 64));
        }
#pragma unroll
        for (int t = 0; t < BN / 32; ++t) {
            int row = w * (BN / 4) + t * 8;
            gload_lds16(BT + (size_t)(n0 + row + lr) * K3 + kk + swz,
                        (void*)(Bs + row * 64));
        }
        __syncthreads();
#pragma unroll
        for (int ks = 0; ks < 2; ++ks) {
            bf16x8_t af[FM], bf[FN];
            const int o = (ks * 4 + fq) ^ fswz;
#pragma unroll
            for (int tm = 0; tm < FM; ++tm) {
                int row = wr * WM + tm * 16 + frow;
                af[tm] = *reinterpret_cast<const bf16x8_t*>(As + row * 64 + o * 8);
            }
#pragma unroll
            for (int tn = 0; tn < FN; ++tn) {
                int row = wc * WN + tn * 16 + frow;
                bf[tn] = *reinterpret_cast<const bf16x8_t*>(Bs + row * 64 + o * 8);
            }
#pragma unroll
            for (int tm = 0; tm < FM; ++tm)
#pragma unroll
                for (int tn = 0; tn < FN; ++tn)
                    acc[tm][tn] = __builtin_amdgcn_mfma_f32_16x16x32_bf16(
                        af[tm], bf[tn], acc[tm][tn], 0, 0, 0);
        }
        __syncthreads();
    }

#pragma unroll
    for (int tn = 0; tn < FN; ++tn) {
        int col = n0 + wc * WN + tn * 16 + (l & 15);
        float bv = bias[col];
#pragma unroll
        for (int tm = 0; tm < FM; ++tm) {
#pragma unroll
            for (int r = 0; r < 4; ++r) {
                int row = m0 + wr * WM + tm * 16 + (l >> 4) * 4 + r;
                float v = fmaxf(acc[tm][tn][r] + bv, 0.f);
                if constexpr (SPLIT) {
                    unsigned short h = f2bf(v);
                    Chi[(size_t)row * N + col] = h;
                    Clo[(size_t)row * N + col] = f2bf(v - bf2f(h));
                } else {
                    Cf[(size_t)row * N + col] = v;
                }
            }
        }
    }
}

// ---------------------------------------------------------------- last layer + log_softmax
__global__ __launch_bounds__(256) void last_layer_kernel(
    const float* __restrict__ A, const float* __restrict__ W,
    const float* __restrict__ b, float* __restrict__ out, int N) {
    constexpr int KD = 128, NC = 13;
    __shared__ float ws[KD * NC];
    __shared__ float bs[NC];
    const int tid = threadIdx.x;
    for (int idx = tid; idx < KD * NC; idx += 256) ws[idx] = W[idx];
    if (tid < NC) bs[tid] = b[tid];
    __syncthreads();
    int r = blockIdx.x * 256 + tid;
    if (r >= N) return;
    float acc[NC];
#pragma unroll
    for (int f = 0; f < NC; ++f) acc[f] = bs[f];
    const float4* row = reinterpret_cast<const float4*>(A + (size_t)r * KD);
#pragma unroll 4
    for (int c4 = 0; c4 < KD / 4; ++c4) {
        float4 v = row[c4];
#pragma unroll
        for (int f = 0; f < NC; ++f) acc[f] += v.x * ws[(c4 * 4 + 0) * NC + f];
#pragma unroll
        for (int f = 0; f < NC; ++f) acc[f] += v.y * ws[(c4 * 4 + 1) * NC + f];
#pragma unroll
        for (int f = 0; f < NC; ++f) acc[f] += v.z * ws[(c4 * 4 + 2) * NC + f];
#pragma unroll
        for (int f = 0; f < NC; ++f) acc[f] += v.w * ws[(c4 * 4 + 3) * NC + f];
    }
    float m = acc[0];
#pragma unroll
    for (int f = 1; f < NC; ++f) m = fmaxf(m, acc[f]);
    float s = 0.f;
#pragma unroll
    for (int f = 0; f < NC; ++f) s += expf(acc[f] - m);
    float ls = logf(s);
#pragma unroll
    for (int f = 0; f < NC; ++f) out[(size_t)r * NC + f] = acc[f] - m - ls;
}

// ---------------------------------------------------------------- launch
extern "C" void kernel_launch(void* const* d_in, const int* in_sizes, int n_in,
                              void* d_out, int out_size, void* d_ws, size_t ws_size,
                              hipStream_t stream) {
    const float* x   = (const float*)d_in[0];
    const float* w1  = (const float*)d_in[1];
    const float* b1  = (const float*)d_in[2];
    const float* w2  = (const float*)d_in[3];
    const float* b2  = (const float*)d_in[4];
    const float* w3  = (const float*)d_in[5];
    const float* b3  = (const float*)d_in[6];
    const float* wl1 = (const float*)d_in[7];
    const float* bl1 = (const float*)d_in[8];
    const float* wm1 = (const float*)d_in[9];
    const float* bm1 = (const float*)d_in[10];
    const float* wm2 = (const float*)d_in[11];
    const float* bm2 = (const float*)d_in[12];
    const float* wm3 = (const float*)d_in[13];
    const float* bm3 = (const float*)d_in[14];
    float* out = (float*)d_out;

    const int N = in_sizes[0] / 3;  // 8192
    const int NCH = N / CHSZ;       // 4 chunks

    float* ws = (float*)d_ws;
    size_t off = 0;
    auto alloc = [&](size_t n) { float* p = ws + off; off += n; return p; };
    float* sq  = alloc(N);
    int*   nbr = (int*)alloc((size_t)N * KNN);
    float* x1  = alloc((size_t)N * 64);
    float* x2  = alloc((size_t)N * 64);
    float* x3  = alloc((size_t)N * 64);
    float* AB  = alloc((size_t)N * 128);
    float* WW  = alloc(64 * 128);
    float* bb  = alloc(128);
    float* sd  = alloc((size_t)N * KNN);
    int*   si  = (int*)alloc((size_t)N * KNN);
    unsigned short* Xs = (unsigned short*)alloc((size_t)N * 192 / 2);       // triple-split [N][192]
    unsigned short* bt1 = (unsigned short*)alloc((size_t)1024 * 576 / 2);   // [1024][576]
    unsigned short* bt2 = (unsigned short*)alloc((size_t)256 * 3072 / 2);   // [256][3072]
    unsigned short* bt3 = (unsigned short*)alloc((size_t)128 * 768 / 2);    // [128][768]
    // union region: D chunk (knn phase) vs head activations (head phase)
    size_t dsz = (size_t)N * CHSZ;  // 16.8M floats > head usage (13.1M)
    float* Z = alloc(dsz);
    float* D = Z;
    unsigned short* cat_hi = (unsigned short*)Z;
    unsigned short* cat_lo = cat_hi + (size_t)N * 192;
    unsigned short* a1_hi  = cat_lo + (size_t)N * 192;
    unsigned short* a1_lo  = a1_hi + (size_t)N * 1024;
    unsigned short* a2_hi  = a1_lo + (size_t)N * 1024;
    unsigned short* a2_lo  = a2_hi + (size_t)N * 256;
    float* a3 = (float*)(a2_lo + (size_t)N * 256);

    // ---- stage 1 (C=3): fused dist+select, single dispatch
    rowsq_kernel<3><<<N / 256, 256, 0, stream>>>(x, sq, N);
    knn3_fused_kernel<<<N / 8, 256, 0, stream>>>(x, sq, nbr, N);
    prep_w_kernel<3><<<2, 256, 0, stream>>>(w1, b1, WW, bb);
    ec_gemm_kernel<3, 8><<<N / 8, 128, 0, stream>>>(x, WW, bb, AB, N);
    ec_max_kernel<<<N / 4, 256, 0, stream>>>(AB, nbr, x1, N);
    // ---- stage 2 (C=64): MFMA distance via exact triple-bf16 split
    rowsq_kernel<64><<<N / 256, 256, 0, stream>>>(x1, sq, N);
    xsplit3_kernel<<<(N * 64 + 255) / 256, 256, 0, stream>>>(x1, Xs, N);
    for (int c = 0; c < NCH; ++c) {
        dist_mfma_kernel<<<dim3(CHSZ / 128, N / 256), 256, 0, stream>>>(Xs, sq, D, c * CHSZ);
        knn_select_kernel<<<N / 4, 256, 0, stream>>>(D, sd, si, nbr, c * CHSZ, c == 0, c == NCH - 1);
    }
    prep_w_kernel<64><<<32, 256, 0, stream>>>(w2, b2, WW, bb);
    ec_gemm_kernel<64, 8><<<N / 8, 128, 0, stream>>>(x1, WW, bb, AB, N);
    ec_max_kernel<<<N / 4, 256, 0, stream>>>(AB, nbr, x2, N);
    // ---- stage 3 (C=64)
    rowsq_kernel<64><<<N / 256, 256, 0, stream>>>(x2, sq, N);
    xsplit3_kernel<<<(N * 64 + 255) / 256, 256, 0, stream>>>(x2, Xs, N);
    for (int c = 0; c < NCH; ++c) {
        dist_mfma_kernel<<<dim3(CHSZ / 128, N / 256), 256, 0, stream>>>(Xs, sq, D, c * CHSZ);
        knn_select_kernel<<<N / 4, 256, 0, stream>>>(D, sd, si, nbr, c * CHSZ, c == 0, c == NCH - 1);
    }
    prep_w_kernel<64><<<32, 256, 0, stream>>>(w3, b3, WW, bb);
    ec_gemm_kernel<64, 8><<<N / 8, 128, 0, stream>>>(x2, WW, bb, AB, N);
    ec_max_kernel<<<N / 4, 256, 0, stream>>>(AB, nbr, x3, N);
    // ---- MLP head (split-bf16 MFMA)
    prep_bsplit_kernel<<<(1024 * 576 + 255) / 256, 256, 0, stream>>>(wl1, bt1, 192, 1024);
    prep_bsplit_kernel<<<(256 * 3072 + 255) / 256, 256, 0, stream>>>(wm1, bt2, 1024, 256);
    prep_bsplit_kernel<<<(128 * 768 + 255) / 256, 256, 0, stream>>>(wm2, bt3, 256, 128);
    concat_split_kernel<<<(N * 192 + 255) / 256, 256, 0, stream>>>(x1, x2, x3, cat_hi, cat_lo, N);
    mfma_gemm_kernel<128, 128, 64, 64, 1><<<dim3(1024 / 128, N / 128), 256, 0, stream>>>(
        cat_hi, cat_lo, bt1, bl1, nullptr, a1_hi, a1_lo, N, 1024, 192);
    mfma_gemm_kernel<64, 64, 32, 32, 1><<<dim3(256 / 64, N / 64), 256, 0, stream>>>(
        a1_hi, a1_lo, bt2, bm1, nullptr, a2_hi, a2_lo, N, 256, 1024);
    mfma_gemm_kernel<64, 64, 32, 32, 0><<<dim3(128 / 64, N / 64), 256, 0, stream>>>(
        a2_hi, a2_lo, bt3, bm2, a3, nullptr, nullptr, N, 128, 256);
    last_layer_kernel<<<(N + 255) / 256, 256, 0, stream>>>(a3, wm3, bm3, out, N);
}

// Round 9
// 577.023 us; speedup vs baseline: 1.0708x; 1.0708x over previous
//
#include <hip/hip_runtime.h>
#include <hip/hip_bf16.h>
#include <math.h>

#define KNN 20
#define CHSZ 2048   // candidate chunk size for distance matrix

typedef __attribute__((ext_vector_type(8))) short bf16x8_t;
typedef __attribute__((ext_vector_type(4))) float f32x4_t;

// bf16 split helpers (RNE)
__device__ __forceinline__ unsigned short f2bf(float f) {
    unsigned u = __float_as_uint(f);
    u += 0x7fffu + ((u >> 16) & 1u);
    return (unsigned short)(u >> 16);
}
__device__ __forceinline__ float bf2f(unsigned short h) {
    return __uint_as_float((unsigned)h << 16);
}

// async global->LDS, 16 B per lane; dest = wave-uniform base + lane*16
__device__ __forceinline__ void gload_lds16(const void* g, void* l) {
    auto gp = reinterpret_cast<const __attribute__((address_space(1))) unsigned*>(
        reinterpret_cast<uintptr_t>(g));
    auto lp = reinterpret_cast<__attribute__((address_space(3))) unsigned*>(
        reinterpret_cast<uintptr_t>(l));
    __builtin_amdgcn_global_load_lds(gp, lp, 16, 0, 0);
}

// 64-lane bitonic ascending sort of one float per lane; returns lane-19 value.
// tau = 20th order statistic of the 64 per-lane minima over the scanned set.
// Validity: the set's top-20 occupy <=20 lanes; each such lane's min <= its
// smallest top-20 member, all other lane minima > d20(set) -> the 20th
// smallest lane-min >= d20(set) >= global d20. Filtering with v <= tau never
// rejects a final top-20 member.
__device__ __forceinline__ float seed_tau(float mv, int l) {
#pragma unroll
    for (int k = 2; k <= 64; k <<= 1) {
#pragma unroll
        for (int j = k >> 1; j > 0; j >>= 1) {
            float o = __shfl_xor(mv, j);
            bool keepMin = (((l & j) == 0) == ((l & k) == 0));
            mv = keepMin ? fminf(mv, o) : fmaxf(mv, o);
        }
    }
    return __shfl(mv, 19);
}

// ---------------------------------------------------------------- rowsq
template<int C>
__global__ void rowsq_kernel(const float* __restrict__ x, float* __restrict__ sq, int N) {
    int i = blockIdx.x * blockDim.x + threadIdx.x;
    if (i >= N) return;
    float s = 0.f;
    if constexpr (C == 64) {
        const float4* p = reinterpret_cast<const float4*>(x + (size_t)i * C);
#pragma unroll
        for (int c = 0; c < 16; ++c) {
            float4 v = p[c];
            s += v.x * v.x + v.y * v.y + v.z * v.z + v.w * v.w;
        }
    } else {
#pragma unroll
        for (int c = 0; c < C; ++c) { float v = x[(size_t)i * C + c]; s += v * v; }
    }
    sq[i] = s;
}

// ---------------------------------------------------------------- triple-bf16 split
// fp32 = h + l + m (exactly, 3x8 significand bits). Xs[row][0:64)=h,
// [64:128)=l, [128:192)=m.
__global__ void xsplit3_kernel(const float* __restrict__ X,
                               unsigned short* __restrict__ Xs, int N) {
    int t = blockIdx.x * 256 + threadIdx.x;
    if (t >= N * 64) return;
    int r = t >> 6, c = t & 63;
    float v = X[t];
    unsigned short h = f2bf(v);
    float r1 = v - bf2f(h);
    unsigned short lo = f2bf(r1);
    float r2 = r1 - bf2f(lo);
    unsigned short mm = f2bf(r2);
    Xs[(size_t)r * 192 + c] = h;
    Xs[(size_t)r * 192 + 64 + c] = lo;
    Xs[(size_t)r * 192 + 128 + c] = mm;
}

// ---------------------------------------------------------------- dist MFMA (C=64)
// (round-7 proven version)
// D[m][n] = sq[m] + sq[j] - 2 * dot(X[m], X[j]), dot via 6-term split-bf16
// MFMA (terms {mh, hh, hl, hm, lh, ll}; dropped terms <= 2^-25 rel).
// All 3 B segments staged ONCE (48 KB LDS); A staged per-segment (16 KB),
// terms grouped by A-seg: m->{h}, h->{h,l,m}, l->{h,l}. af cached for both
// ks in registers; B=h fragments (used by ALL 3 A-segs) cached in registers
// at ai=0 -> 16 fewer ds_read_b128/wave. 5 barriers; 64 KB LDS -> 2 blk/CU.
__global__ __launch_bounds__(256) void dist_mfma_kernel(
    const unsigned short* __restrict__ Xs, const float* __restrict__ sq,
    float* __restrict__ D, int chunk_base) {
    __shared__ __align__(16) unsigned short As[128 * 64];       // 16 KB (current A-seg)
    __shared__ __align__(16) unsigned short Bs[3 * 128 * 64];   // 48 KB (segs h,l,m)
    const int tid = threadIdx.x;
    const int w = tid >> 6, l = tid & 63;
    const int wr = w & 1, wc = w >> 1;
    const int m0 = blockIdx.y * 128;
    const int n0 = blockIdx.x * 128;          // chunk-local
    const int jb = chunk_base + n0;           // global candidate base
    const int lr = l >> 3;
    const int swz = ((l & 7) ^ lr) * 8;
    const int frow = l & 15;
    const int fq = l >> 4;
    const int fswz = l & 7;

    f32x4_t acc[4][4];
#pragma unroll
    for (int a = 0; a < 4; ++a)
#pragma unroll
        for (int b = 0; b < 4; ++b) acc[a][b] = (f32x4_t){0.f, 0.f, 0.f, 0.f};

    // stage B: all three segs (sub-buffer 0=h(+0), 1=l(+64), 2=m(+128))
#pragma unroll
    for (int sgi = 0; sgi < 3; ++sgi) {
#pragma unroll
        for (int s = 0; s < 4; ++s) {
            int row = w * 32 + s * 8;
            gload_lds16(Xs + (size_t)(jb + row + lr) * 192 + sgi * 64 + swz,
                        (void*)(Bs + sgi * 8192 + row * 64));
        }
    }

    // A-seg order m(+128), h(+0), l(+64); B partners {h} / {h,l,m} / {h,l}
    bf16x8_t bfh[2][4];   // cached B=h fragments, reused across all 3 A-segs
#pragma unroll
    for (int ai = 0; ai < 3; ++ai) {
        constexpr int aoffs[3] = {128, 0, 64};
        constexpr int bcnts[3] = {1, 3, 2};
        if (ai) __syncthreads();          // all waves done reading prior As
#pragma unroll
        for (int s = 0; s < 4; ++s) {
            int row = w * 32 + s * 8;
            gload_lds16(Xs + (size_t)(m0 + row + lr) * 192 + aoffs[ai] + swz,
                        (void*)(As + row * 64));
        }
        __syncthreads();                   // staging visible (incl. B on ai=0)
        bf16x8_t af[2][4];
#pragma unroll
        for (int ks = 0; ks < 2; ++ks) {
            const int o = (ks * 4 + fq) ^ fswz;
#pragma unroll
            for (int tm = 0; tm < 4; ++tm)
                af[ks][tm] = *reinterpret_cast<const bf16x8_t*>(
                    As + (wr * 64 + tm * 16 + frow) * 64 + o * 8);
            if (ai == 0) {
#pragma unroll
                for (int tn = 0; tn < 4; ++tn)
                    bfh[ks][tn] = *reinterpret_cast<const bf16x8_t*>(
                        Bs + (wc * 64 + tn * 16 + frow) * 64 + o * 8);
            }
        }
        // bi = 0: B = h from register cache (same acc order as LDS path)
#pragma unroll
        for (int ks = 0; ks < 2; ++ks)
#pragma unroll
            for (int tm = 0; tm < 4; ++tm)
#pragma unroll
                for (int tn = 0; tn < 4; ++tn)
                    acc[tm][tn] = __builtin_amdgcn_mfma_f32_16x16x32_bf16(
                        af[ks][tm], bfh[ks][tn], acc[tm][tn], 0, 0, 0);
#pragma unroll
        for (int bi = 1; bi < bcnts[ai]; ++bi) {
            const unsigned short* Bseg = Bs + bi * 8192;
#pragma unroll
            for (int ks = 0; ks < 2; ++ks) {
                const int o = (ks * 4 + fq) ^ fswz;
                bf16x8_t bf[4];
#pragma unroll
                for (int tn = 0; tn < 4; ++tn)
                    bf[tn] = *reinterpret_cast<const bf16x8_t*>(
                        Bseg + (wc * 64 + tn * 16 + frow) * 64 + o * 8);
#pragma unroll
                for (int tm = 0; tm < 4; ++tm)
#pragma unroll
                    for (int tn = 0; tn < 4; ++tn)
                        acc[tm][tn] = __builtin_amdgcn_mfma_f32_16x16x32_bf16(
                            af[ks][tm], bf[tn], acc[tm][tn], 0, 0, 0);
            }
        }
    }

    // epilogue: C/D layout col=lane&15, row=(lane>>4)*4+reg
    float sn[4]; int jn[4], nc[4];
#pragma unroll
    for (int tn = 0; tn < 4; ++tn) {
        nc[tn] = wc * 64 + tn * 16 + (l & 15);
        jn[tn] = jb + nc[tn];
        sn[tn] = sq[jn[tn]];
    }
#pragma unroll
    for (int tm = 0; tm < 4; ++tm) {
#pragma unroll
        for (int r = 0; r < 4; ++r) {
            int m = m0 + wr * 64 + tm * 16 + (l >> 4) * 4 + r;
            float sm = sq[m];
#pragma unroll
            for (int tn = 0; tn < 4; ++tn) {
                float val = sm + sn[tn] - 2.f * acc[tm][tn][r];
                if (m == jn[tn]) val = INFINITY;
                D[(size_t)m * CHSZ + n0 + nc[tn]] = val;
            }
        }
    }
}

// ---------------------------------------------------------------- knn select (C=64 path)
// One wave per point; distributed sorted top-20 (lanes 0..19), lex (d,idx)
// order == jax.lax.top_k tie-break. All 32 values register-resident; per-chunk
// tau (20th of lane minima, exact bound); tf = min(tau_chunk, carried d19).
__global__ __launch_bounds__(256) void knn_select_kernel(
    const float* __restrict__ D, float* __restrict__ sd, int* __restrict__ si,
    int* __restrict__ nbrs, int chunk_base, int first, int last) {
    const int tid = threadIdx.x;
    const int w = tid >> 6, l = tid & 63;
    const int p = blockIdx.x * 4 + w;

    float dl = INFINITY; int il = 0x7fffffff;
    if (!first && l < KNN) { dl = sd[(size_t)p * KNN + l]; il = si[(size_t)p * KNN + l]; }
    float d19 = __shfl(dl, 19);

    const float4* Drow = reinterpret_cast<const float4*>(D + (size_t)p * CHSZ);
    float4 v[8];
#pragma unroll
    for (int b = 0; b < 8; ++b) v[b] = Drow[b * 64 + l];

    // per-chunk tau from the register-resident values (diag already INF)
    float mn = INFINITY;
#pragma unroll
    for (int b = 0; b < 8; ++b)
        mn = fminf(mn, fminf(fminf(v[b].x, v[b].y), fminf(v[b].z, v[b].w)));
    const float tau = seed_tau(mn, l);
    const float tf = fminf(tau, d19);

#pragma unroll
    for (int b = 0; b < 8; ++b) {
        bool q0 = v[b].x <= tf, q1 = v[b].y <= tf, q2 = v[b].z <= tf, q3 = v[b].w <= tf;
        unsigned long long anyb = __ballot(q0 | q1 | q2 | q3);
        if (!anyb) continue;
#pragma unroll
        for (int qq = 0; qq < 4; ++qq) {
            float vq = (qq == 0) ? v[b].x : (qq == 1) ? v[b].y : (qq == 2) ? v[b].z : v[b].w;
            unsigned long long bal = __ballot((qq == 0) ? q0 : (qq == 1) ? q1 : (qq == 2) ? q2 : q3);
            while (bal) {
                int ln = __ffsll((unsigned long long)bal) - 1;
                bal &= bal - 1;
                float cv = __shfl(vq, ln);
                int cj = chunk_base + b * 256 + 4 * ln + qq;
                bool cmp = (dl < cv) || (dl == cv && il < cj);
                unsigned long long cb = __ballot(cmp) & 0xFFFFFull;
                int r = __popcll(cb);
                float sdl = __shfl_up(dl, 1);
                int sil = __shfl_up(il, 1);
                if (l == r) { dl = cv; il = cj; }
                else if (l > r && l < KNN) { dl = sdl; il = sil; }
            }
        }
    }
    if (l < KNN) {
        sd[(size_t)p * KNN + l] = dl;
        si[(size_t)p * KNN + l] = il;
        if (last) nbrs[(size_t)p * KNN + l] = il;
    }
}

// ---------------------------------------------------------------- knn fused (C=3), 2 points/wave
// Multi-query two-pass (proven round-7 structure): grid N/8 = 1024 blocks ->
// 4 waves/SIMD; pass 1 exact tau, pass 2 filtered scan + exact lex insert.
__global__ __launch_bounds__(256) void knn3_fused_kernel(
    const float* __restrict__ X, const float* __restrict__ sq,
    int* __restrict__ nbrs, int N) {
    const int tid = threadIdx.x;
    const int w = tid >> 6, l = tid & 63;
    const int p0 = blockIdx.x * 8 + w * 2;   // points p0, p0+1
    float qx[2], qy[2], qz[2], sp4[2];
#pragma unroll
    for (int pp = 0; pp < 2; ++pp) {
        qx[pp] = X[(size_t)(p0 + pp) * 3];
        qy[pp] = X[(size_t)(p0 + pp) * 3 + 1];
        qz[pp] = X[(size_t)(p0 + pp) * 3 + 2];
        sp4[pp] = sq[p0 + pp];
    }
    const int ptile = p0 & ~255;   // both points share this 256-tile

    // ---- pass 1: per-lane minima for both points
    float mn[2];
#pragma unroll
    for (int pp = 0; pp < 2; ++pp) mn[pp] = INFINITY;
    {
        const float4* xr0 = reinterpret_cast<const float4*>(X + (size_t)(4 * l) * 3);
        float4 nr0 = xr0[0], nr1 = xr0[1], nr2 = xr0[2];
        float4 nsj = *reinterpret_cast<const float4*>(sq + 4 * l);
#pragma unroll 1
        for (int j0 = 0; j0 < N; j0 += 256) {
            const int jl = j0 + 4 * l;
            float4 r0 = nr0, r1 = nr1, r2 = nr2, sj = nsj;
            if (j0 + 256 < N) {
                const float4* xn = reinterpret_cast<const float4*>(X + (size_t)(jl + 256) * 3);
                nr0 = xn[0]; nr1 = xn[1]; nr2 = xn[2];
                nsj = *reinterpret_cast<const float4*>(sq + jl + 256);
            }
            float cx[4] = {r0.x, r0.w, r1.z, r2.y};
            float cy[4] = {r0.y, r1.x, r1.w, r2.z};
            float cz[4] = {r0.z, r1.y, r2.x, r2.w};
            float sjc[4] = {sj.x, sj.y, sj.z, sj.w};
            float v[2][4];
#pragma unroll
            for (int pp = 0; pp < 2; ++pp)
#pragma unroll
                for (int c = 0; c < 4; ++c) {
                    float t = qx[pp] * cx[c];
                    t = fmaf(qy[pp], cy[c], t);
                    t = fmaf(qz[pp], cz[c], t);
                    v[pp][c] = fmaf(-2.f, t, sp4[pp] + sjc[c]);
                }
            if (j0 == ptile) {
#pragma unroll
                for (int pp = 0; pp < 2; ++pp)
#pragma unroll
                    for (int c = 0; c < 4; ++c)
                        if (jl + c == p0 + pp) v[pp][c] = INFINITY;
            }
#pragma unroll
            for (int pp = 0; pp < 2; ++pp)
                mn[pp] = fminf(mn[pp], fminf(fminf(v[pp][0], v[pp][1]),
                                             fminf(v[pp][2], v[pp][3])));
        }
    }
    float tau[2];
#pragma unroll
    for (int pp = 0; pp < 2; ++pp) tau[pp] = seed_tau(mn[pp], l);

    // ---- pass 2: filter with constant tau[pp] + exact lex insert
    float dl[2]; int il[2];
#pragma unroll
    for (int pp = 0; pp < 2; ++pp) { dl[pp] = INFINITY; il[pp] = 0x7fffffff; }
    const float4* xr0 = reinterpret_cast<const float4*>(X + (size_t)(4 * l) * 3);
    float4 nr0 = xr0[0], nr1 = xr0[1], nr2 = xr0[2];
    float4 nsj = *reinterpret_cast<const float4*>(sq + 4 * l);

#pragma unroll 1
    for (int j0 = 0; j0 < N; j0 += 256) {
        const int jl = j0 + 4 * l;
        float4 r0 = nr0, r1 = nr1, r2 = nr2, sj = nsj;
        if (j0 + 256 < N) {
            const float4* xn = reinterpret_cast<const float4*>(X + (size_t)(jl + 256) * 3);
            nr0 = xn[0]; nr1 = xn[1]; nr2 = xn[2];
            nsj = *reinterpret_cast<const float4*>(sq + jl + 256);
        }
        float cx[4] = {r0.x, r0.w, r1.z, r2.y};
        float cy[4] = {r0.y, r1.x, r1.w, r2.z};
        float cz[4] = {r0.z, r1.y, r2.x, r2.w};
        float sjc[4] = {sj.x, sj.y, sj.z, sj.w};
        float v[2][4];
#pragma unroll
        for (int pp = 0; pp < 2; ++pp)
#pragma unroll
            for (int c = 0; c < 4; ++c) {
                float t = qx[pp] * cx[c];
                t = fmaf(qy[pp], cy[c], t);
                t = fmaf(qz[pp], cz[c], t);
                v[pp][c] = fmaf(-2.f, t, sp4[pp] + sjc[c]);
            }
        if (j0 == ptile) {
#pragma unroll
            for (int pp = 0; pp < 2; ++pp)
#pragma unroll
                for (int c = 0; c < 4; ++c)
                    if (jl + c == p0 + pp) v[pp][c] = INFINITY;
        }
#pragma unroll
        for (int pp = 0; pp < 2; ++pp) {
            bool q0 = v[pp][0] <= tau[pp], q1 = v[pp][1] <= tau[pp];
            bool q2 = v[pp][2] <= tau[pp], q3 = v[pp][3] <= tau[pp];
            unsigned long long anyb = __ballot(q0 | q1 | q2 | q3);
            if (!anyb) continue;
#pragma unroll
            for (int qq = 0; qq < 4; ++qq) {
                float vq = v[pp][qq];
                unsigned long long bal = __ballot((qq == 0) ? q0 : (qq == 1) ? q1 : (qq == 2) ? q2 : q3);
                while (bal) {
                    int ln = __ffsll((unsigned long long)bal) - 1;
                    bal &= bal - 1;
                    float cv = __shfl(vq, ln);
                    int cj = j0 + 4 * ln + qq;
                    bool cmp = (dl[pp] < cv) || (dl[pp] == cv && il[pp] < cj);
                    unsigned long long cb = __ballot(cmp) & 0xFFFFFull;
                    int r = __popcll(cb);
                    float sdl = __shfl_up(dl[pp], 1);
                    int sil = __shfl_up(il[pp], 1);
                    if (l == r) { dl[pp] = cv; il[pp] = cj; }
                    else if (l > r && l < KNN) { dl[pp] = sdl; il[pp] = sil; }
                }
            }
        }
    }
    if (l < KNN) {
#pragma unroll
        for (int pp = 0; pp < 2; ++pp)
            nbrs[(size_t)(p0 + pp) * KNN + l] = il[pp];
    }
}

// ---------------------------------------------------------------- edgeconv weight prep (all 3, one dispatch)
// Same per-element math as the old per-stage prep_w kernels; three disjoint
// t-ranges write three dedicated WW/bb buffers.
__global__ void prep_w_all_kernel(
    const float* __restrict__ w1, const float* __restrict__ b1,
    float* __restrict__ WW1, float* __restrict__ bb1,
    const float* __restrict__ w2, const float* __restrict__ b2,
    float* __restrict__ WW2, float* __restrict__ bb2,
    const float* __restrict__ w3, const float* __restrict__ b3,
    float* __restrict__ WW3, float* __restrict__ bb3) {
    int t = blockIdx.x * 256 + threadIdx.x;
    if (t < 512) {
        if (t < 128) bb1[t] = (t < 64) ? b1[t] : 0.f;
        if (t < 3 * 128) {
            int c = t >> 7, f = t & 127;
            WW1[t] = (f < 64) ? (w1[c * 64 + f] - w1[(3 + c) * 64 + f])
                              : w1[(3 + c) * 64 + (f - 64)];
        }
    } else if (t < 512 + 8192) {
        int u = t - 512;
        if (u < 128) bb2[u] = (u < 64) ? b2[u] : 0.f;
        int c = u >> 7, f = u & 127;
        WW2[u] = (f < 64) ? (w2[c * 64 + f] - w2[(64 + c) * 64 + f])
                          : w2[(64 + c) * 64 + (f - 64)];
    } else if (t < 512 + 16384) {
        int u = t - (512 + 8192);
        if (u < 128) bb3[u] = (u < 64) ? b3[u] : 0.f;
        int c = u >> 7, f = u & 127;
        WW3[u] = (f < 64) ? (w3[c * 64 + f] - w3[(64 + c) * 64 + f])
                          : w3[(64 + c) * 64 + (f - 64)];
    }
}

template<int C, int ROWS>
__global__ __launch_bounds__(128) void ec_gemm_kernel(
    const float* __restrict__ x, const float* __restrict__ WW,
    const float* __restrict__ bb, float* __restrict__ AB, int N) {
    __shared__ float Ws[C * 128];
    __shared__ float xs[ROWS * C];
    const int tid = threadIdx.x;
    const int r0 = blockIdx.x * ROWS;
    for (int idx = tid; idx < C * 32; idx += 128)
        reinterpret_cast<float4*>(Ws)[idx] = reinterpret_cast<const float4*>(WW)[idx];
    for (int idx = tid; idx < ROWS * C / 4; idx += 128)
        reinterpret_cast<float4*>(xs)[idx] =
            reinterpret_cast<const float4*>(x + (size_t)r0 * C)[idx];
    __syncthreads();
    const float bias = bb[tid];
#pragma unroll 1
    for (int r = 0; r < ROWS; ++r) {
        float acc = bias;
#pragma unroll
        for (int c = 0; c < C; ++c) acc = fmaf(xs[r * C + c], Ws[c * 128 + tid], acc);
        AB[(size_t)(r0 + r) * 128 + tid] = acc;
    }
}

__global__ __launch_bounds__(256) void ec_max_kernel(
    const float* __restrict__ AB, const int* __restrict__ nbrs,
    float* __restrict__ out, int N) {
    const int tid = threadIdx.x;
    const int w = tid >> 6, f = tid & 63;
    const int i = blockIdx.x * 4 + w;
    const float a = AB[(size_t)i * 128 + f];
    const int* nb = nbrs + (size_t)i * KNN;
    float m = -3.4e38f;
#pragma unroll
    for (int j = 0; j < KNN; ++j) {
        int n = nb[j];
        m = fmaxf(m, AB[(size_t)n * 128 + 64 + f]);
    }
    out[(size_t)i * 64 + f] = fmaxf(a + m, 0.f);
}

// ---------------------------------------------------------------- concat + split to bf16 hi/lo
__global__ void concat_split_kernel(const float* __restrict__ a, const float* __restrict__ b,
                                    const float* __restrict__ c,
                                    unsigned short* __restrict__ hi, unsigned short* __restrict__ lo,
                                    int N) {
    int t = blockIdx.x * blockDim.x + threadIdx.x;
    if (t >= N * 192) return;
    int r = t / 192, cc = t % 192;
    float v;
    if (cc < 64) v = a[(size_t)r * 64 + cc];
    else if (cc < 128) v = b[(size_t)r * 64 + cc - 64];
    else v = c[(size_t)r * 64 + cc - 128];
    unsigned short h = f2bf(v);
    hi[t] = h;
    lo[t] = f2bf(v - bf2f(h));
}

// ---------------------------------------------------------------- weight split (all 3 head weights, one dispatch)
// Same per-element math as the old per-layer prep_bsplit; three disjoint
// t-ranges write the three BT buffers.
__global__ void prep_bsplit_all_kernel(
    const float* __restrict__ wl1, unsigned short* __restrict__ bt1,
    const float* __restrict__ wm1, unsigned short* __restrict__ bt2,
    const float* __restrict__ wm2, unsigned short* __restrict__ bt3) {
    int t = blockIdx.x * 256 + threadIdx.x;
    const float* W; unsigned short* BT; int K, F, u;
    if (t < 589824)        { W = wl1; BT = bt1; K = 192;  F = 1024; u = t; }
    else if (t < 1376256)  { W = wm1; BT = bt2; K = 1024; F = 256;  u = t - 589824; }
    else if (t < 1474560)  { W = wm2; BT = bt3; K = 256;  F = 128;  u = t - 1376256; }
    else return;
    int K3 = 3 * K;
    int n = u / K3, kp = u - n * K3;
    int seg = kp / K;
    int k = kp - seg * K;
    float v = W[(size_t)k * F + n];
    unsigned short h = f2bf(v);
    BT[u] = (seg == 1) ? f2bf(v - bf2f(h)) : h;
}

// ---------------------------------------------------------------- split-bf16 MFMA GEMM
// Per-wave tile WM x WN (frag counts FM=WM/16, FN=WN/16), 4 waves per block.
template<int BM, int BN, int WM, int WN, int SPLIT>
__global__ __launch_bounds__(256) void mfma_gemm_kernel(
    const unsigned short* __restrict__ Ahi, const unsigned short* __restrict__ Alo,
    const unsigned short* __restrict__ BT, const float* __restrict__ bias,
    float* __restrict__ Cf, unsigned short* __restrict__ Chi, unsigned short* __restrict__ Clo,
    int M, int N, int K) {
    constexpr int WR = BM / WM, WC = BN / WN;
    static_assert(WR * WC == 4, "4 waves");
    constexpr int FM = WM / 16, FN = WN / 16;
    __shared__ __align__(16) unsigned short As[BM * 64];
    __shared__ __align__(16) unsigned short Bs[BN * 64];
    const int tid = threadIdx.x;
    const int w = tid >> 6, l = tid & 63;
    const int wr = w % WR, wc = w / WR;
    const int m0 = blockIdx.y * BM, n0 = blockIdx.x * BN;
    const int K3 = 3 * K;

    f32x4_t acc[FM][FN];
#pragma unroll
    for (int a = 0; a < FM; ++a)
#pragma unroll
        for (int b = 0; b < FN; ++b) acc[a][b] = (f32x4_t){0.f, 0.f, 0.f, 0.f};

    const int lr = l >> 3;
    const int swz = ((l & 7) ^ lr) * 8;
    const int frow = l & 15;
    const int fq = l >> 4;
    const int fswz = l & 7;

    for (int kt = 0; kt < K3 / 64; ++kt) {
        const int kk = kt * 64;
        const unsigned short* srcA; int k0;
        if (kk < K)            { srcA = Ahi; k0 = kk; }
        else if (kk < 2 * K)   { srcA = Ahi; k0 = kk - K; }
        else                   { srcA = Alo; k0 = kk - 2 * K; }
#pragma unroll
        for (int t = 0; t < BM / 32; ++t) {
            int row = w * (BM / 4) + t * 8;
            gload_lds16(srcA + (size_t)(m0 + row + lr) * K + k0 + swz,
                        (void*)(As + row * 64));
        }
#pragma unroll
        for (int t = 0; t < BN / 32; ++t) {
            int row = w * (BN / 4) + t * 8;
            gload_lds16(BT + (size_t)(n0 + row + lr) * K3 + kk + swz,
                        (void*)(Bs + row * 64));
        }
        __syncthreads();
#pragma unroll
        for (int ks = 0; ks < 2; ++ks) {
            bf16x8_t af[FM], bf[FN];
            const int o = (ks * 4 + fq) ^ fswz;
#pragma unroll
            for (int tm = 0; tm < FM; ++tm) {
                int row = wr * WM + tm * 16 + frow;
                af[tm] = *reinterpret_cast<const bf16x8_t*>(As + row * 64 + o * 8);
            }
#pragma unroll
            for (int tn = 0; tn < FN; ++tn) {
                int row = wc * WN + tn * 16 + frow;
                bf[tn] = *reinterpret_cast<const bf16x8_t*>(Bs + row * 64 + o * 8);
            }
#pragma unroll
            for (int tm = 0; tm < FM; ++tm)
#pragma unroll
                for (int tn = 0; tn < FN; ++tn)
                    acc[tm][tn] = __builtin_amdgcn_mfma_f32_16x16x32_bf16(
                        af[tm], bf[tn], acc[tm][tn], 0, 0, 0);
        }
        __syncthreads();
    }

#pragma unroll
    for (int tn = 0; tn < FN; ++tn) {
        int col = n0 + wc * WN + tn * 16 + (l & 15);
        float bv = bias[col];
#pragma unroll
        for (int tm = 0; tm < FM; ++tm) {
#pragma unroll
            for (int r = 0; r < 4; ++r) {
                int row = m0 + wr * WM + tm * 16 + (l >> 4) * 4 + r;
                float v = fmaxf(acc[tm][tn][r] + bv, 0.f);
                if constexpr (SPLIT) {
                    unsigned short h = f2bf(v);
                    Chi[(size_t)row * N + col] = h;
                    Clo[(size_t)row * N + col] = f2bf(v - bf2f(h));
                } else {
                    Cf[(size_t)row * N + col] = v;
                }
            }
        }
    }
}

// ---------------------------------------------------------------- last layer + log_softmax
__global__ __launch_bounds__(256) void last_layer_kernel(
    const float* __restrict__ A, const float* __restrict__ W,
    const float* __restrict__ b, float* __restrict__ out, int N) {
    constexpr int KD = 128, NC = 13;
    __shared__ float ws[KD * NC];
    __shared__ float bs[NC];
    const int tid = threadIdx.x;
    for (int idx = tid; idx < KD * NC; idx += 256) ws[idx] = W[idx];
    if (tid < NC) bs[tid] = b[tid];
    __syncthreads();
    int r = blockIdx.x * 256 + tid;
    if (r >= N) return;
    float acc[NC];
#pragma unroll
    for (int f = 0; f < NC; ++f) acc[f] = bs[f];
    const float4* row = reinterpret_cast<const float4*>(A + (size_t)r * KD);
#pragma unroll 4
    for (int c4 = 0; c4 < KD / 4; ++c4) {
        float4 v = row[c4];
#pragma unroll
        for (int f = 0; f < NC; ++f) acc[f] += v.x * ws[(c4 * 4 + 0) * NC + f];
#pragma unroll
        for (int f = 0; f < NC; ++f) acc[f] += v.y * ws[(c4 * 4 + 1) * NC + f];
#pragma unroll
        for (int f = 0; f < NC; ++f) acc[f] += v.z * ws[(c4 * 4 + 2) * NC + f];
#pragma unroll
        for (int f = 0; f < NC; ++f) acc[f] += v.w * ws[(c4 * 4 + 3) * NC + f];
    }
    float m = acc[0];
#pragma unroll
    for (int f = 1; f < NC; ++f) m = fmaxf(m, acc[f]);
    float s = 0.f;
#pragma unroll
    for (int f = 0; f < NC; ++f) s += expf(acc[f] - m);
    float ls = logf(s);
#pragma unroll
    for (int f = 0; f < NC; ++f) out[(size_t)r * NC + f] = acc[f] - m - ls;
}

// ---------------------------------------------------------------- launch
extern "C" void kernel_launch(void* const* d_in, const int* in_sizes, int n_in,
                              void* d_out, int out_size, void* d_ws, size_t ws_size,
                              hipStream_t stream) {
    const float* x   = (const float*)d_in[0];
    const float* w1  = (const float*)d_in[1];
    const float* b1  = (const float*)d_in[2];
    const float* w2  = (const float*)d_in[3];
    const float* b2  = (const float*)d_in[4];
    const float* w3  = (const float*)d_in[5];
    const float* b3  = (const float*)d_in[6];
    const float* wl1 = (const float*)d_in[7];
    const float* bl1 = (const float*)d_in[8];
    const float* wm1 = (const float*)d_in[9];
    const float* bm1 = (const float*)d_in[10];
    const float* wm2 = (const float*)d_in[11];
    const float* bm2 = (const float*)d_in[12];
    const float* wm3 = (const float*)d_in[13];
    const float* bm3 = (const float*)d_in[14];
    float* out = (float*)d_out;

    const int N = in_sizes[0] / 3;  // 8192
    const int NCH = N / CHSZ;       // 4 chunks

    float* ws = (float*)d_ws;
    size_t off = 0;
    auto alloc = [&](size_t n) { float* p = ws + off; off += n; return p; };
    float* sq  = alloc(N);
    int*   nbr = (int*)alloc((size_t)N * KNN);
    float* x1  = alloc((size_t)N * 64);
    float* x2  = alloc((size_t)N * 64);
    float* x3  = alloc((size_t)N * 64);
    float* AB  = alloc((size_t)N * 128);
    float* WW1 = alloc(512);
    float* bb1 = alloc(128);
    float* WW2 = alloc(64 * 128);
    float* bb2 = alloc(128);
    float* WW3 = alloc(64 * 128);
    float* bb3 = alloc(128);
    float* sd  = alloc((size_t)N * KNN);
    int*   si  = (int*)alloc((size_t)N * KNN);
    unsigned short* Xs = (unsigned short*)alloc((size_t)N * 192 / 2);       // triple-split [N][192]
    unsigned short* bt1 = (unsigned short*)alloc((size_t)1024 * 576 / 2);   // [1024][576]
    unsigned short* bt2 = (unsigned short*)alloc((size_t)256 * 3072 / 2);   // [256][3072]
    unsigned short* bt3 = (unsigned short*)alloc((size_t)128 * 768 / 2);    // [128][768]
    // union region: D chunk (knn phase) vs head activations (head phase)
    size_t dsz = (size_t)N * CHSZ;  // 16.8M floats > head usage (13.1M)
    float* Z = alloc(dsz);
    float* D = Z;
    unsigned short* cat_hi = (unsigned short*)Z;
    unsigned short* cat_lo = cat_hi + (size_t)N * 192;
    unsigned short* a1_hi  = cat_lo + (size_t)N * 192;
    unsigned short* a1_lo  = a1_hi + (size_t)N * 1024;
    unsigned short* a2_hi  = a1_lo + (size_t)N * 1024;
    unsigned short* a2_lo  = a2_hi + (size_t)N * 256;
    float* a3 = (float*)(a2_lo + (size_t)N * 256);

    // ---- weight prep for all 3 EdgeConv stages (one dispatch, no WW reuse hazard)
    prep_w_all_kernel<<<(512 + 16384 + 255) / 256, 256, 0, stream>>>(
        w1, b1, WW1, bb1, w2, b2, WW2, bb2, w3, b3, WW3, bb3);
    // ---- stage 1 (C=3): fused dist+select, single dispatch
    rowsq_kernel<3><<<N / 256, 256, 0, stream>>>(x, sq, N);
    knn3_fused_kernel<<<N / 8, 256, 0, stream>>>(x, sq, nbr, N);
    ec_gemm_kernel<3, 8><<<N / 8, 128, 0, stream>>>(x, WW1, bb1, AB, N);
    ec_max_kernel<<<N / 4, 256, 0, stream>>>(AB, nbr, x1, N);
    // ---- stage 2 (C=64): MFMA distance via exact triple-bf16 split
    rowsq_kernel<64><<<N / 256, 256, 0, stream>>>(x1, sq, N);
    xsplit3_kernel<<<(N * 64 + 255) / 256, 256, 0, stream>>>(x1, Xs, N);
    for (int c = 0; c < NCH; ++c) {
        dist_mfma_kernel<<<dim3(CHSZ / 128, N / 128), 256, 0, stream>>>(Xs, sq, D, c * CHSZ);
        knn_select_kernel<<<N / 4, 256, 0, stream>>>(D, sd, si, nbr, c * CHSZ, c == 0, c == NCH - 1);
    }
    ec_gemm_kernel<64, 8><<<N / 8, 128, 0, stream>>>(x1, WW2, bb2, AB, N);
    ec_max_kernel<<<N / 4, 256, 0, stream>>>(AB, nbr, x2, N);
    // ---- stage 3 (C=64)
    rowsq_kernel<64><<<N / 256, 256, 0, stream>>>(x2, sq, N);
    xsplit3_kernel<<<(N * 64 + 255) / 256, 256, 0, stream>>>(x2, Xs, N);
    for (int c = 0; c < NCH; ++c) {
        dist_mfma_kernel<<<dim3(CHSZ / 128, N / 128), 256, 0, stream>>>(Xs, sq, D, c * CHSZ);
        knn_select_kernel<<<N / 4, 256, 0, stream>>>(D, sd, si, nbr, c * CHSZ, c == 0, c == NCH - 1);
    }
    ec_gemm_kernel<64, 8><<<N / 8, 128, 0, stream>>>(x2, WW3, bb3, AB, N);
    ec_max_kernel<<<N / 4, 256, 0, stream>>>(AB, nbr, x3, N);
    // ---- MLP head (split-bf16 MFMA)
    prep_bsplit_all_kernel<<<(1474560 + 255) / 256, 256, 0, stream>>>(
        wl1, bt1, wm1, bt2, wm2, bt3);
    concat_split_kernel<<<(N * 192 + 255) / 256, 256, 0, stream>>>(x1, x2, x3, cat_hi, cat_lo, N);
    mfma_gemm_kernel<128, 128, 64, 64, 1><<<dim3(1024 / 128, N / 128), 256, 0, stream>>>(
        cat_hi, cat_lo, bt1, bl1, nullptr, a1_hi, a1_lo, N, 1024, 192);
    mfma_gemm_kernel<64, 64, 32, 32, 1><<<dim3(256 / 64, N / 64), 256, 0, stream>>>(
        a1_hi, a1_lo, bt2, bm1, nullptr, a2_hi, a2_lo, N, 256, 1024);
    mfma_gemm_kernel<64, 64, 32, 32, 0><<<dim3(128 / 64, N / 64), 256, 0, stream>>>(
        a2_hi, a2_lo, bt3, bm2, a3, nullptr, nullptr, N, 128, 256);
    last_layer_kernel<<<(N + 255) / 256, 256, 0, stream>>>(a3, wm3, bm3, out, N);
}